// Round 6
// baseline (954.001 us; speedup 1.0000x reference)
//
#include <hip/hip_runtime.h>
#include <hip/hip_bf16.h>

#define N_NODES 100000
#define G_PART 8      // node groups (XCD-striped)
#define B_PART 64     // blocks per group
#define NPG_MAX 12512 // LDS histogram capacity (>= ceil(N/8))

// ---------------------------------------------------------------- CSR build
// R5 insight: device-scope atomicAdd is memory-side (non-coherent per-XCD L2s
// -> coherence point past L2): 3.2M atomics = ~100MB of HBM-side 32B ops in
// BOTH count and fill (count's WRITE_SIZE was 99.8MB for a 400KB array).
// Fix: no global atomics at all. LDS histogram per (group, block) + per-node
// per-block exclusive prefix -> fill positions come from LDS atomics only.

// count: block (g,b) sweeps edge slice b, histograms dst in group g's range
// into LDS, flushes partial counts with plain coalesced stores.
__global__ __launch_bounds__(256) void count_hist(const int* __restrict__ dst, int E,
                                                  int Epb, int* __restrict__ partial,
                                                  int npg, int N) {
    __shared__ int hist[NPG_MAX];
    int g = blockIdx.x & (G_PART - 1);
    int b = blockIdx.x / G_PART;
    int lo = g * npg;
    int hi = min(lo + npg, N);
    int tid = threadIdx.x;
    for (int i = tid; i < npg; i += 256) hist[i] = 0;
    __syncthreads();
    int ibeg = b * Epb + tid;
    int iend = min((b + 1) * Epb, E);
    for (int i = ibeg; i < iend; i += 256) {
        int d = __builtin_nontemporal_load(dst + i);
        if (d >= lo && d < hi) atomicAdd(&hist[d - lo], 1);
    }
    __syncthreads();
    int base = (g * B_PART + b) * npg;
    for (int i = tid; i < npg; i += 256) partial[base + i] = hist[i];
}

// per node: exclusive prefix across the B_PART block-partials (in place),
// total -> cnt. Coalesced: fixed b => adjacent nodes are adjacent addresses.
__global__ __launch_bounds__(256) void scan_partials(int* __restrict__ partial,
                                                     int* __restrict__ cnt,
                                                     int npg, int N) {
    int n = blockIdx.x * 256 + threadIdx.x;
    if (n >= N) return;
    int g = n / npg;
    int i = n - g * npg;
    int base = g * B_PART * npg + i;
    int run = 0;
#pragma unroll 4
    for (int b = 0; b < B_PART; ++b) {
        int idx = base + b * npg;
        int t = partial[idx];
        partial[idx] = run;
        run += t;
    }
    cnt[n] = run;
}

// fill: LDS cursor = row_off + per-block base; LDS atomicAdd for position;
// plain store to csr_src (positions disjoint across blocks by construction).
__global__ __launch_bounds__(256) void fill_hist(const int* __restrict__ src,
                                                 const int* __restrict__ dst, int E,
                                                 int Epb, const int* __restrict__ partial,
                                                 const int* __restrict__ row_off,
                                                 int* __restrict__ csr_src,
                                                 int npg, int N) {
    __shared__ int cur[NPG_MAX];
    int g = blockIdx.x & (G_PART - 1);
    int b = blockIdx.x / G_PART;
    int lo = g * npg;
    int hi = min(lo + npg, N);
    int tid = threadIdx.x;
    int pbase = (g * B_PART + b) * npg;
    for (int i = tid; i < npg && lo + i < N; i += 256)
        cur[i] = row_off[lo + i] + partial[pbase + i];
    __syncthreads();
    int ibeg = b * Epb + tid;
    int iend = min((b + 1) * Epb, E);
    for (int i = ibeg; i < iend; i += 256) {
        int d = __builtin_nontemporal_load(dst + i);
        int s = __builtin_nontemporal_load(src + i);
        if (d >= lo && d < hi) {
            int p = atomicAdd(&cur[d - lo], 1);
            csr_src[p] = s;
        }
    }
}

// ---------------- grid-parallel exclusive scan (3 kernels, 1024 elems/block)
#define SCHUNK 1024

__global__ __launch_bounds__(256) void scan_blocks(const int* __restrict__ cnt,
                                                   int* __restrict__ row_off,
                                                   int* __restrict__ block_sums, int n) {
    __shared__ int ts[256];
    int tid = threadIdx.x;
    int base = blockIdx.x * SCHUNK + tid * 4;
    int v[4];
    int s = 0;
#pragma unroll
    for (int j = 0; j < 4; ++j) {
        int i = base + j;
        v[j] = (i < n) ? cnt[i] : 0;
        s += v[j];
    }
    ts[tid] = s;
    __syncthreads();
    for (int off = 1; off < 256; off <<= 1) {
        int t = 0;
        if (tid >= off) t = ts[tid - off];
        __syncthreads();
        if (tid >= off) ts[tid] += t;
        __syncthreads();
    }
    int run = (tid > 0) ? ts[tid - 1] : 0;
    if (tid == 255) block_sums[blockIdx.x] = ts[255];
#pragma unroll
    for (int j = 0; j < 4; ++j) {
        int i = base + j;
        if (i < n) row_off[i] = run;
        run += v[j];
    }
}

__global__ __launch_bounds__(256) void scan_sums(int* __restrict__ block_sums, int nb,
                                                 int* __restrict__ row_off, int n) {
    __shared__ int ts[256];
    int tid = threadIdx.x;
    int v = (tid < nb) ? block_sums[tid] : 0;
    ts[tid] = v;
    __syncthreads();
    for (int off = 1; off < 256; off <<= 1) {
        int t = 0;
        if (tid >= off) t = ts[tid - off];
        __syncthreads();
        if (tid >= off) ts[tid] += t;
        __syncthreads();
    }
    if (tid < nb) block_sums[tid] = (tid > 0) ? ts[tid - 1] : 0;
    if (tid == 255) row_off[n] = ts[255];
}

__global__ __launch_bounds__(256) void scan_add(int* __restrict__ row_off,
                                                const int* __restrict__ block_sums, int n) {
    int tid = threadIdx.x;
    int off = block_sums[blockIdx.x];
    int base = blockIdx.x * SCHUNK + tid * 4;
#pragma unroll
    for (int j = 0; j < 4; ++j) {
        int i = base + j;
        if (i < n) row_off[i] += off;
    }
}

// ---------------------------------------------------------------- bf16 pack
__global__ __launch_bounds__(256) void pack_bf16(const float* __restrict__ in,
                                                 uint2* __restrict__ out, int n4) {
    int i = blockIdx.x * 256 + threadIdx.x;
    if (i >= n4) return;
    float4 v = *(const float4*)&in[(size_t)i * 4];
    __hip_bfloat162 p0 = __float22bfloat162_rn(make_float2(v.x, v.y));
    __hip_bfloat162 p1 = __float22bfloat162_rn(make_float2(v.z, v.w));
    uint2 o;
    o.x = *(const uint*)&p0;
    o.y = *(const uint*)&p1;
    out[i] = o;
}

// ------------------------------------------------- mean aggregation, bf16 gather
static __device__ inline float2 unpack2(uint v) {
    float2 r;
    r.x = __uint_as_float(v << 16);
    r.y = __uint_as_float(v & 0xffff0000u);
    return r;
}

__global__ __launch_bounds__(256) void agg_bf16(const uint* __restrict__ featb,
                                                const int* __restrict__ row_off,
                                                const int* __restrict__ csr,
                                                float* __restrict__ outf, int M) {
    int node = blockIdx.x * 4 + (threadIdx.x >> 6);
    if (node >= M) return;
    int lane = threadIdx.x & 63;
    int beg = row_off[node], end = row_off[node + 1];
    float sx = 0.f, sy = 0.f;
    int i = beg;
    for (; i + 4 <= end; i += 4) {
        int s0 = csr[i], s1 = csr[i + 1], s2 = csr[i + 2], s3 = csr[i + 3];
        uint v0 = featb[(size_t)s0 * 64 + lane];
        uint v1 = featb[(size_t)s1 * 64 + lane];
        uint v2 = featb[(size_t)s2 * 64 + lane];
        uint v3 = featb[(size_t)s3 * 64 + lane];
        float2 f0 = unpack2(v0), f1 = unpack2(v1), f2 = unpack2(v2), f3 = unpack2(v3);
        sx += f0.x + f1.x + f2.x + f3.x;
        sy += f0.y + f1.y + f2.y + f3.y;
    }
    for (; i < end; ++i) {
        uint v = featb[(size_t)csr[i] * 64 + lane];
        float2 f = unpack2(v);
        sx += f.x;
        sy += f.y;
    }
    float inv = (end > beg) ? 1.0f / (float)(end - beg) : 0.0f;
    float2 o;
    o.x = sx * inv;
    o.y = sy * inv;
    ((float2*)outf)[(size_t)node * 64 + lane] = o;
}

// --------------------------------------------- fused dual GEMM: out = act(A1@W1^T + A2@W2^T + b)
#define BM 64
#define KB 32
__global__ __launch_bounds__(256) void gemm_dual(const float* __restrict__ A1,
                                                 const float* __restrict__ A2,
                                                 const float* __restrict__ W1,
                                                 const float* __restrict__ W2,
                                                 const float* __restrict__ bias,
                                                 float* __restrict__ out,
                                                 uint2* __restrict__ outb,   // nullable
                                                 int M, int relu) {
    __shared__ float As[KB][BM + 4];
    __shared__ float Ws[KB][128 + 4];
    int tid = threadIdx.x;
    int row0 = blockIdx.x * BM;
    int tr = tid >> 5;
    int tc = tid & 31;
    int r0 = tr * 8;
    int c0 = tc * 4;
    float acc[8][4];
#pragma unroll
    for (int i = 0; i < 8; ++i)
#pragma unroll
        for (int c = 0; c < 4; ++c) acc[i][c] = 0.f;

    for (int half = 0; half < 2; ++half) {
        const float* A = half ? A2 : A1;
        const float* W = half ? W2 : W1;
        for (int kc = 0; kc < 128; kc += KB) {
#pragma unroll
            for (int t = 0; t < 2; ++t) {
                int f = tid + t * 256;
                int r = f >> 3;
                int c4 = (f & 7) * 4;
                int gr = row0 + r;
                float4 v = make_float4(0.f, 0.f, 0.f, 0.f);
                if (gr < M) v = *(const float4*)&A[(size_t)gr * 128 + kc + c4];
                As[c4 + 0][r] = v.x;
                As[c4 + 1][r] = v.y;
                As[c4 + 2][r] = v.z;
                As[c4 + 3][r] = v.w;
            }
#pragma unroll
            for (int t = 0; t < 4; ++t) {
                int f = tid + t * 256;
                int j = f >> 3;
                int c4 = (f & 7) * 4;
                float4 v = *(const float4*)&W[(size_t)j * 128 + kc + c4];
                Ws[c4 + 0][j] = v.x;
                Ws[c4 + 1][j] = v.y;
                Ws[c4 + 2][j] = v.z;
                Ws[c4 + 3][j] = v.w;
            }
            __syncthreads();
#pragma unroll
            for (int k = 0; k < KB; ++k) {
                float4 a0 = *(const float4*)&As[k][r0];
                float4 a1 = *(const float4*)&As[k][r0 + 4];
                float4 bv = *(const float4*)&Ws[k][c0];
                float av[8] = {a0.x, a0.y, a0.z, a0.w, a1.x, a1.y, a1.z, a1.w};
                float bb[4] = {bv.x, bv.y, bv.z, bv.w};
#pragma unroll
                for (int i = 0; i < 8; ++i)
#pragma unroll
                    for (int c = 0; c < 4; ++c) acc[i][c] += av[i] * bb[c];
            }
            __syncthreads();
        }
    }
#pragma unroll
    for (int i = 0; i < 8; ++i) {
        int gr = row0 + r0 + i;
        if (gr < M) {
            float4 o;
            o.x = acc[i][0] + bias[c0 + 0];
            o.y = acc[i][1] + bias[c0 + 1];
            o.z = acc[i][2] + bias[c0 + 2];
            o.w = acc[i][3] + bias[c0 + 3];
            if (relu) {
                o.x = fmaxf(o.x, 0.f);
                o.y = fmaxf(o.y, 0.f);
                o.z = fmaxf(o.z, 0.f);
                o.w = fmaxf(o.w, 0.f);
            }
            *(float4*)&out[(size_t)gr * 128 + c0] = o;
            if (outb) {
                __hip_bfloat162 p0 = __float22bfloat162_rn(make_float2(o.x, o.y));
                __hip_bfloat162 p1 = __float22bfloat162_rn(make_float2(o.z, o.w));
                uint2 ob;
                ob.x = *(const uint*)&p0;
                ob.y = *(const uint*)&p1;
                outb[(size_t)gr * 32 + (c0 >> 2)] = ob;
            }
        }
    }
}

// ------------------------------------- layer 3 transform: zr[n][0..5]=h@Wl3^T, [6..11]=h@Wr3^T+b3
__global__ __launch_bounds__(256) void lin3_kernel(const float* __restrict__ h,
                                                   const float* __restrict__ Wl,
                                                   const float* __restrict__ Wr,
                                                   const float* __restrict__ b3,
                                                   float* __restrict__ zr, int M) {
    __shared__ float Ws[12][129];
    __shared__ float hs[16][132];
    int tid = threadIdx.x;
    for (int f = tid; f < 12 * 128; f += 256) {
        int j = f >> 7, k = f & 127;
        Ws[j][k] = (j < 6) ? Wl[j * 128 + k] : Wr[(j - 6) * 128 + k];
    }
    int node0 = blockIdx.x * 16;
#pragma unroll
    for (int t = 0; t < 2; ++t) {
        int f = tid + t * 256;
        int r = f >> 5;
        int c4 = (f & 31) * 4;
        int gn = node0 + r;
        float4 v = make_float4(0.f, 0.f, 0.f, 0.f);
        if (gn < M) v = *(const float4*)&h[(size_t)gn * 128 + c4];
        *(float4*)&hs[r][c4] = v;
    }
    __syncthreads();
    int ln = tid >> 4;
    int j = tid & 15;
    int gn = node0 + ln;
    if (j < 12 && gn < M) {
        float acc = 0.f;
#pragma unroll
        for (int k = 0; k < 128; ++k) acc += hs[ln][k] * Ws[j][k];
        if (j >= 6) acc += b3[j - 6];
        zr[(size_t)gn * 12 + j] = acc;
    }
}

// ------------------------------------------- final: out[n][j] = mean_s z[s][j] + r[n][j]
__global__ void out_kernel(const float* __restrict__ zr, const int* __restrict__ row_off,
                           const int* __restrict__ csr, float* __restrict__ out, int M) {
    int idx = blockIdx.x * blockDim.x + threadIdx.x;
    int node = idx >> 3;
    int j = idx & 7;
    if (node >= M || j >= 6) return;
    int beg = row_off[node], end = row_off[node + 1];
    float acc = 0.f;
    for (int i = beg; i < end; ++i) {
        int s = csr[i];
        acc += zr[(size_t)s * 12 + j];
    }
    float inv = (end > beg) ? 1.0f / (float)(end - beg) : 0.0f;
    out[(size_t)node * 6 + j] = acc * inv + zr[(size_t)node * 12 + 6 + j];
}

// ---------------------------------------------------------------- launch
static inline size_t align_up(size_t x, size_t a) { return (x + a - 1) & ~(a - 1); }

extern "C" void kernel_launch(void* const* d_in, const int* in_sizes, int n_in,
                              void* d_out, int out_size, void* d_ws, size_t ws_size,
                              hipStream_t stream) {
    const float* x = (const float*)d_in[0];
    const int* ei = (const int*)d_in[1];
    const float* Wl1 = (const float*)d_in[2];
    const float* Wr1 = (const float*)d_in[3];
    const float* b1 = (const float*)d_in[4];
    const float* Wl2 = (const float*)d_in[5];
    const float* Wr2 = (const float*)d_in[6];
    const float* b2 = (const float*)d_in[7];
    const float* Wl3 = (const float*)d_in[8];
    const float* Wr3 = (const float*)d_in[9];
    const float* b3 = (const float*)d_in[10];

    const int N = in_sizes[0] / 128;   // 100000
    const int E = in_sizes[1] / 2;     // 3200000
    const int* src = ei;
    const int* dst = ei + E;

    // workspace layout
    char* ws = (char*)d_ws;
    size_t off = 0;
    int* cnt = (int*)(ws + off);        off = align_up(off + (size_t)N * 4, 512);
    int* row_off = (int*)(ws + off);    off = align_up(off + (size_t)(N + 1) * 4, 512);
    int* block_sums = (int*)(ws + off); off = align_up(off + 512 * 4, 512);
    int* csr_src = (int*)(ws + off);    off = align_up(off + (size_t)E * 4, 512);
    float* aggn = (float*)(ws + off);   off = align_up(off + (size_t)N * 128 * 4, 512);
    float* h1 = (float*)(ws + off);     off = align_up(off + (size_t)N * 128 * 4, 512);
    float* h2 = (float*)(ws + off);     off = align_up(off + (size_t)N * 128 * 4, 512);
    float* zr = (float*)(ws + off);     off = align_up(off + (size_t)N * 12 * 4, 512);
    uint2* h1b = (uint2*)(ws + off);    off = align_up(off + (size_t)N * 128 * 2, 512);
    // partial aliases aggn (live [count, fill]; aggn live [agg1, gemm2]) — disjoint.
    int* partial = (int*)aggn;          // G*B*npg ints = 25.6 MB < 51.2 MB
    // xb aliases h2 (live [pack, agg1]; h2 live [gemm2, out]) — disjoint.
    uint2* xb = (uint2*)h2;
    (void)ws_size;

    // --- CSR build: LDS-histogram, zero global atomics ---
    const int npg = (N + G_PART - 1) / G_PART;       // 12500 (<= NPG_MAX)
    const int Epb = (E + B_PART - 1) / B_PART;       // 50000
    const int build_grid = G_PART * B_PART;          // 512 blocks

    count_hist<<<build_grid, 256, 0, stream>>>(dst, E, Epb, partial, npg, N);
    scan_partials<<<(N + 255) / 256, 256, 0, stream>>>(partial, cnt, npg, N);

    const int nscan = (N + SCHUNK - 1) / SCHUNK;
    scan_blocks<<<nscan, 256, 0, stream>>>(cnt, row_off, block_sums, N);
    scan_sums<<<1, 256, 0, stream>>>(block_sums, nscan, row_off, N);
    scan_add<<<nscan, 256, 0, stream>>>(row_off, block_sums, N);

    fill_hist<<<build_grid, 256, 0, stream>>>(src, dst, E, Epb, partial, row_off,
                                              csr_src, npg, N);

    // pack x -> bf16 (gather payload halved)
    const int n4 = N * 32;
    pack_bf16<<<(n4 + 255) / 256, 256, 0, stream>>>(x, xb, n4);

    int aggGrid = (N + 3) / 4;
    int gemmGrid = (N + BM - 1) / BM;

    // layer 1
    agg_bf16<<<aggGrid, 256, 0, stream>>>((const uint*)xb, row_off, csr_src, aggn, N);
    gemm_dual<<<gemmGrid, 256, 0, stream>>>(aggn, x, Wl1, Wr1, b1, h1, h1b, N, 1);
    // layer 2
    agg_bf16<<<aggGrid, 256, 0, stream>>>((const uint*)h1b, row_off, csr_src, aggn, N);
    gemm_dual<<<gemmGrid, 256, 0, stream>>>(aggn, h1, Wl2, Wr2, b2, h2, nullptr, N, 1);
    // layer 3
    lin3_kernel<<<(N + 15) / 16, 256, 0, stream>>>(h2, Wl3, Wr3, b3, zr, N);
    out_kernel<<<(N * 8 + 255) / 256, 256, 0, stream>>>(zr, row_off, csr_src, (float*)d_out, N);
}

// Round 7
// 828.683 us; speedup vs baseline: 1.1512x; 1.1512x over previous
//
#include <hip/hip_runtime.h>
#include <hip/hip_bf16.h>

#define N_NODES 100000
#define G_PART 16     // node groups (XCD-striped); npg = 6250 -> 25 KB LDS
#define B_PART 96     // slice-blocks per group; grid 1536 = 6 blocks/CU (LDS cap)
#define NPG_PAD 6272  // LDS histogram capacity (>= ceil(N/G_PART))

// ---------------------------------------------------------------- CSR build
// R5: device atomics are memory-side (~23 G/s, 32B HBM ops) -> LDS histograms.
// R6: 50KB LDS capped occupancy at 21.8% -> latency-bound at 202us. Fix: G=16
// (25KB LDS, 6 blocks/CU), grid 1536, 4-wide load unroll, conditional src load.

__global__ __launch_bounds__(256) void count_hist(const int* __restrict__ dst, int E,
                                                  int Epb, int* __restrict__ partial,
                                                  int npg, int N) {
    __shared__ int hist[NPG_PAD];
    int g = blockIdx.x & (G_PART - 1);
    int b = blockIdx.x / G_PART;
    int lo = g * npg;
    int hi = min(lo + npg, N);
    int tid = threadIdx.x;
    for (int i = tid; i < npg; i += 256) hist[i] = 0;
    __syncthreads();
    int ibeg = b * Epb + tid;
    int iend = min((b + 1) * Epb, E);
    int i = ibeg;
    for (; i + 768 < iend; i += 1024) {
        int d0 = __builtin_nontemporal_load(dst + i);
        int d1 = __builtin_nontemporal_load(dst + i + 256);
        int d2 = __builtin_nontemporal_load(dst + i + 512);
        int d3 = __builtin_nontemporal_load(dst + i + 768);
        if (d0 >= lo && d0 < hi) atomicAdd(&hist[d0 - lo], 1);
        if (d1 >= lo && d1 < hi) atomicAdd(&hist[d1 - lo], 1);
        if (d2 >= lo && d2 < hi) atomicAdd(&hist[d2 - lo], 1);
        if (d3 >= lo && d3 < hi) atomicAdd(&hist[d3 - lo], 1);
    }
    for (; i < iend; i += 256) {
        int d = __builtin_nontemporal_load(dst + i);
        if (d >= lo && d < hi) atomicAdd(&hist[d - lo], 1);
    }
    __syncthreads();
    int base = (g * B_PART + b) * npg;
    for (int j = tid; j < npg; j += 256) partial[base + j] = hist[j];
}

// per node: exclusive prefix across the B_PART block-partials (in place),
// total -> cnt. Coalesced: fixed b => adjacent nodes are adjacent addresses.
__global__ __launch_bounds__(256) void scan_partials(int* __restrict__ partial,
                                                     int* __restrict__ cnt,
                                                     int npg, int N) {
    int n = blockIdx.x * 256 + threadIdx.x;
    if (n >= N) return;
    int g = n / npg;
    int i = n - g * npg;
    size_t base = (size_t)g * B_PART * npg + i;
    int run = 0;
#pragma unroll 4
    for (int b = 0; b < B_PART; ++b) {
        size_t idx = base + (size_t)b * npg;
        int t = partial[idx];
        partial[idx] = run;
        run += t;
    }
    cnt[n] = run;
}

// fill: LDS cursor = row_off + per-block base; LDS atomicAdd for position;
// plain store to csr_src (positions disjoint across blocks by construction).
__global__ __launch_bounds__(256) void fill_hist(const int* __restrict__ src,
                                                 const int* __restrict__ dst, int E,
                                                 int Epb, const int* __restrict__ partial,
                                                 const int* __restrict__ row_off,
                                                 int* __restrict__ csr_src,
                                                 int npg, int N) {
    __shared__ int cur[NPG_PAD];
    int g = blockIdx.x & (G_PART - 1);
    int b = blockIdx.x / G_PART;
    int lo = g * npg;
    int hi = min(lo + npg, N);
    int tid = threadIdx.x;
    size_t pbase = (size_t)(g * B_PART + b) * npg;
    for (int i = tid; i < npg && lo + i < N; i += 256)
        cur[i] = row_off[lo + i] + partial[pbase + i];
    __syncthreads();
    int ibeg = b * Epb + tid;
    int iend = min((b + 1) * Epb, E);
    int i = ibeg;
    for (; i + 768 < iend; i += 1024) {
        int d0 = __builtin_nontemporal_load(dst + i);
        int d1 = __builtin_nontemporal_load(dst + i + 256);
        int d2 = __builtin_nontemporal_load(dst + i + 512);
        int d3 = __builtin_nontemporal_load(dst + i + 768);
        if (d0 >= lo && d0 < hi) {
            int p = atomicAdd(&cur[d0 - lo], 1);
            csr_src[p] = src[i];
        }
        if (d1 >= lo && d1 < hi) {
            int p = atomicAdd(&cur[d1 - lo], 1);
            csr_src[p] = src[i + 256];
        }
        if (d2 >= lo && d2 < hi) {
            int p = atomicAdd(&cur[d2 - lo], 1);
            csr_src[p] = src[i + 512];
        }
        if (d3 >= lo && d3 < hi) {
            int p = atomicAdd(&cur[d3 - lo], 1);
            csr_src[p] = src[i + 768];
        }
    }
    for (; i < iend; i += 256) {
        int d = __builtin_nontemporal_load(dst + i);
        if (d >= lo && d < hi) {
            int p = atomicAdd(&cur[d - lo], 1);
            csr_src[p] = src[i];
        }
    }
}

// ---------------- grid-parallel exclusive scan (3 kernels, 1024 elems/block)
#define SCHUNK 1024

__global__ __launch_bounds__(256) void scan_blocks(const int* __restrict__ cnt,
                                                   int* __restrict__ row_off,
                                                   int* __restrict__ block_sums, int n) {
    __shared__ int ts[256];
    int tid = threadIdx.x;
    int base = blockIdx.x * SCHUNK + tid * 4;
    int v[4];
    int s = 0;
#pragma unroll
    for (int j = 0; j < 4; ++j) {
        int i = base + j;
        v[j] = (i < n) ? cnt[i] : 0;
        s += v[j];
    }
    ts[tid] = s;
    __syncthreads();
    for (int off = 1; off < 256; off <<= 1) {
        int t = 0;
        if (tid >= off) t = ts[tid - off];
        __syncthreads();
        if (tid >= off) ts[tid] += t;
        __syncthreads();
    }
    int run = (tid > 0) ? ts[tid - 1] : 0;
    if (tid == 255) block_sums[blockIdx.x] = ts[255];
#pragma unroll
    for (int j = 0; j < 4; ++j) {
        int i = base + j;
        if (i < n) row_off[i] = run;
        run += v[j];
    }
}

__global__ __launch_bounds__(256) void scan_sums(int* __restrict__ block_sums, int nb,
                                                 int* __restrict__ row_off, int n) {
    __shared__ int ts[256];
    int tid = threadIdx.x;
    int v = (tid < nb) ? block_sums[tid] : 0;
    ts[tid] = v;
    __syncthreads();
    for (int off = 1; off < 256; off <<= 1) {
        int t = 0;
        if (tid >= off) t = ts[tid - off];
        __syncthreads();
        if (tid >= off) ts[tid] += t;
        __syncthreads();
    }
    if (tid < nb) block_sums[tid] = (tid > 0) ? ts[tid - 1] : 0;
    if (tid == 255) row_off[n] = ts[255];
}

__global__ __launch_bounds__(256) void scan_add(int* __restrict__ row_off,
                                                const int* __restrict__ block_sums, int n) {
    int tid = threadIdx.x;
    int off = block_sums[blockIdx.x];
    int base = blockIdx.x * SCHUNK + tid * 4;
#pragma unroll
    for (int j = 0; j < 4; ++j) {
        int i = base + j;
        if (i < n) row_off[i] += off;
    }
}

// ---------------------------------------------------------------- bf16 pack
__global__ __launch_bounds__(256) void pack_bf16(const float* __restrict__ in,
                                                 uint2* __restrict__ out, int n4) {
    int i = blockIdx.x * 256 + threadIdx.x;
    if (i >= n4) return;
    float4 v = *(const float4*)&in[(size_t)i * 4];
    __hip_bfloat162 p0 = __float22bfloat162_rn(make_float2(v.x, v.y));
    __hip_bfloat162 p1 = __float22bfloat162_rn(make_float2(v.z, v.w));
    uint2 o;
    o.x = *(const uint*)&p0;
    o.y = *(const uint*)&p1;
    out[i] = o;
}

// ------------------------------------------------- mean aggregation, bf16 gather
static __device__ inline float2 unpack2(uint v) {
    float2 r;
    r.x = __uint_as_float(v << 16);
    r.y = __uint_as_float(v & 0xffff0000u);
    return r;
}

__global__ __launch_bounds__(256) void agg_bf16(const uint* __restrict__ featb,
                                                const int* __restrict__ row_off,
                                                const int* __restrict__ csr,
                                                float* __restrict__ outf, int M) {
    int node = blockIdx.x * 4 + (threadIdx.x >> 6);
    if (node >= M) return;
    int lane = threadIdx.x & 63;
    int beg = row_off[node], end = row_off[node + 1];
    float sx = 0.f, sy = 0.f;
    int i = beg;
    for (; i + 4 <= end; i += 4) {
        int s0 = csr[i], s1 = csr[i + 1], s2 = csr[i + 2], s3 = csr[i + 3];
        uint v0 = featb[(size_t)s0 * 64 + lane];
        uint v1 = featb[(size_t)s1 * 64 + lane];
        uint v2 = featb[(size_t)s2 * 64 + lane];
        uint v3 = featb[(size_t)s3 * 64 + lane];
        float2 f0 = unpack2(v0), f1 = unpack2(v1), f2 = unpack2(v2), f3 = unpack2(v3);
        sx += f0.x + f1.x + f2.x + f3.x;
        sy += f0.y + f1.y + f2.y + f3.y;
    }
    for (; i < end; ++i) {
        uint v = featb[(size_t)csr[i] * 64 + lane];
        float2 f = unpack2(v);
        sx += f.x;
        sy += f.y;
    }
    float inv = (end > beg) ? 1.0f / (float)(end - beg) : 0.0f;
    float2 o;
    o.x = sx * inv;
    o.y = sy * inv;
    ((float2*)outf)[(size_t)node * 64 + lane] = o;
}

// --------------------------------------------- fused dual GEMM: out = act(A1@W1^T + A2@W2^T + b)
#define BM 64
#define KB 32
__global__ __launch_bounds__(256) void gemm_dual(const float* __restrict__ A1,
                                                 const float* __restrict__ A2,
                                                 const float* __restrict__ W1,
                                                 const float* __restrict__ W2,
                                                 const float* __restrict__ bias,
                                                 float* __restrict__ out,
                                                 uint2* __restrict__ outb,   // nullable
                                                 int M, int relu) {
    __shared__ float As[KB][BM + 4];
    __shared__ float Ws[KB][128 + 4];
    int tid = threadIdx.x;
    int row0 = blockIdx.x * BM;
    int tr = tid >> 5;
    int tc = tid & 31;
    int r0 = tr * 8;
    int c0 = tc * 4;
    float acc[8][4];
#pragma unroll
    for (int i = 0; i < 8; ++i)
#pragma unroll
        for (int c = 0; c < 4; ++c) acc[i][c] = 0.f;

    for (int half = 0; half < 2; ++half) {
        const float* A = half ? A2 : A1;
        const float* W = half ? W2 : W1;
        for (int kc = 0; kc < 128; kc += KB) {
#pragma unroll
            for (int t = 0; t < 2; ++t) {
                int f = tid + t * 256;
                int r = f >> 3;
                int c4 = (f & 7) * 4;
                int gr = row0 + r;
                float4 v = make_float4(0.f, 0.f, 0.f, 0.f);
                if (gr < M) v = *(const float4*)&A[(size_t)gr * 128 + kc + c4];
                As[c4 + 0][r] = v.x;
                As[c4 + 1][r] = v.y;
                As[c4 + 2][r] = v.z;
                As[c4 + 3][r] = v.w;
            }
#pragma unroll
            for (int t = 0; t < 4; ++t) {
                int f = tid + t * 256;
                int j = f >> 3;
                int c4 = (f & 7) * 4;
                float4 v = *(const float4*)&W[(size_t)j * 128 + kc + c4];
                Ws[c4 + 0][j] = v.x;
                Ws[c4 + 1][j] = v.y;
                Ws[c4 + 2][j] = v.z;
                Ws[c4 + 3][j] = v.w;
            }
            __syncthreads();
#pragma unroll
            for (int k = 0; k < KB; ++k) {
                float4 a0 = *(const float4*)&As[k][r0];
                float4 a1 = *(const float4*)&As[k][r0 + 4];
                float4 bv = *(const float4*)&Ws[k][c0];
                float av[8] = {a0.x, a0.y, a0.z, a0.w, a1.x, a1.y, a1.z, a1.w};
                float bb[4] = {bv.x, bv.y, bv.z, bv.w};
#pragma unroll
                for (int i = 0; i < 8; ++i)
#pragma unroll
                    for (int c = 0; c < 4; ++c) acc[i][c] += av[i] * bb[c];
            }
            __syncthreads();
        }
    }
#pragma unroll
    for (int i = 0; i < 8; ++i) {
        int gr = row0 + r0 + i;
        if (gr < M) {
            float4 o;
            o.x = acc[i][0] + bias[c0 + 0];
            o.y = acc[i][1] + bias[c0 + 1];
            o.z = acc[i][2] + bias[c0 + 2];
            o.w = acc[i][3] + bias[c0 + 3];
            if (relu) {
                o.x = fmaxf(o.x, 0.f);
                o.y = fmaxf(o.y, 0.f);
                o.z = fmaxf(o.z, 0.f);
                o.w = fmaxf(o.w, 0.f);
            }
            *(float4*)&out[(size_t)gr * 128 + c0] = o;
            if (outb) {
                __hip_bfloat162 p0 = __float22bfloat162_rn(make_float2(o.x, o.y));
                __hip_bfloat162 p1 = __float22bfloat162_rn(make_float2(o.z, o.w));
                uint2 ob;
                ob.x = *(const uint*)&p0;
                ob.y = *(const uint*)&p1;
                outb[(size_t)gr * 32 + (c0 >> 2)] = ob;
            }
        }
    }
}

// ------------------------------------- layer 3 transform: zr[n][0..5]=h@Wl3^T, [6..11]=h@Wr3^T+b3
__global__ __launch_bounds__(256) void lin3_kernel(const float* __restrict__ h,
                                                   const float* __restrict__ Wl,
                                                   const float* __restrict__ Wr,
                                                   const float* __restrict__ b3,
                                                   float* __restrict__ zr, int M) {
    __shared__ float Ws[12][129];
    __shared__ float hs[16][132];
    int tid = threadIdx.x;
    for (int f = tid; f < 12 * 128; f += 256) {
        int j = f >> 7, k = f & 127;
        Ws[j][k] = (j < 6) ? Wl[j * 128 + k] : Wr[(j - 6) * 128 + k];
    }
    int node0 = blockIdx.x * 16;
#pragma unroll
    for (int t = 0; t < 2; ++t) {
        int f = tid + t * 256;
        int r = f >> 5;
        int c4 = (f & 31) * 4;
        int gn = node0 + r;
        float4 v = make_float4(0.f, 0.f, 0.f, 0.f);
        if (gn < M) v = *(const float4*)&h[(size_t)gn * 128 + c4];
        *(float4*)&hs[r][c4] = v;
    }
    __syncthreads();
    int ln = tid >> 4;
    int j = tid & 15;
    int gn = node0 + ln;
    if (j < 12 && gn < M) {
        float acc = 0.f;
#pragma unroll
        for (int k = 0; k < 128; ++k) acc += hs[ln][k] * Ws[j][k];
        if (j >= 6) acc += b3[j - 6];
        zr[(size_t)gn * 12 + j] = acc;
    }
}

// ------------------------------------------- final: out[n][j] = mean_s z[s][j] + r[n][j]
__global__ void out_kernel(const float* __restrict__ zr, const int* __restrict__ row_off,
                           const int* __restrict__ csr, float* __restrict__ out, int M) {
    int idx = blockIdx.x * blockDim.x + threadIdx.x;
    int node = idx >> 3;
    int j = idx & 7;
    if (node >= M || j >= 6) return;
    int beg = row_off[node], end = row_off[node + 1];
    float acc = 0.f;
    for (int i = beg; i < end; ++i) {
        int s = csr[i];
        acc += zr[(size_t)s * 12 + j];
    }
    float inv = (end > beg) ? 1.0f / (float)(end - beg) : 0.0f;
    out[(size_t)node * 6 + j] = acc * inv + zr[(size_t)node * 12 + 6 + j];
}

// ---------------------------------------------------------------- launch
static inline size_t align_up(size_t x, size_t a) { return (x + a - 1) & ~(a - 1); }

extern "C" void kernel_launch(void* const* d_in, const int* in_sizes, int n_in,
                              void* d_out, int out_size, void* d_ws, size_t ws_size,
                              hipStream_t stream) {
    const float* x = (const float*)d_in[0];
    const int* ei = (const int*)d_in[1];
    const float* Wl1 = (const float*)d_in[2];
    const float* Wr1 = (const float*)d_in[3];
    const float* b1 = (const float*)d_in[4];
    const float* Wl2 = (const float*)d_in[5];
    const float* Wr2 = (const float*)d_in[6];
    const float* b2 = (const float*)d_in[7];
    const float* Wl3 = (const float*)d_in[8];
    const float* Wr3 = (const float*)d_in[9];
    const float* b3 = (const float*)d_in[10];

    const int N = in_sizes[0] / 128;   // 100000
    const int E = in_sizes[1] / 2;     // 3200000
    const int* src = ei;
    const int* dst = ei + E;

    // workspace layout
    char* ws = (char*)d_ws;
    size_t off = 0;
    int* cnt = (int*)(ws + off);        off = align_up(off + (size_t)N * 4, 512);
    int* row_off = (int*)(ws + off);    off = align_up(off + (size_t)(N + 1) * 4, 512);
    int* block_sums = (int*)(ws + off); off = align_up(off + 512 * 4, 512);
    int* csr_src = (int*)(ws + off);    off = align_up(off + (size_t)E * 4, 512);
    float* aggn = (float*)(ws + off);   off = align_up(off + (size_t)N * 128 * 4, 512);
    float* h1 = (float*)(ws + off);     off = align_up(off + (size_t)N * 128 * 4, 512);
    float* h2 = (float*)(ws + off);     off = align_up(off + (size_t)N * 128 * 4, 512);
    float* zr = (float*)(ws + off);     off = align_up(off + (size_t)N * 12 * 4, 512);
    uint2* h1b = (uint2*)(ws + off);    off = align_up(off + (size_t)N * 128 * 2, 512);
    // partial aliases aggn (live [count, fill]; aggn live [agg1, gemm2]) — disjoint.
    // size: G*B*npg = 16*96*6250*4 = 38.4 MB < 51.2 MB ✓
    int* partial = (int*)aggn;
    // xb aliases h2 (live [pack, agg1]; h2 live [gemm2, out]) — disjoint.
    uint2* xb = (uint2*)h2;
    (void)ws_size;

    // --- CSR build: LDS-histogram, zero global atomics ---
    const int npg = (N + G_PART - 1) / G_PART;       // 6250 (<= NPG_PAD)
    const int Epb = (E + B_PART - 1) / B_PART;       // 33334
    const int build_grid = G_PART * B_PART;          // 1536 blocks = 6/CU

    count_hist<<<build_grid, 256, 0, stream>>>(dst, E, Epb, partial, npg, N);
    scan_partials<<<(N + 255) / 256, 256, 0, stream>>>(partial, cnt, npg, N);

    const int nscan = (N + SCHUNK - 1) / SCHUNK;
    scan_blocks<<<nscan, 256, 0, stream>>>(cnt, row_off, block_sums, N);
    scan_sums<<<1, 256, 0, stream>>>(block_sums, nscan, row_off, N);
    scan_add<<<nscan, 256, 0, stream>>>(row_off, block_sums, N);

    fill_hist<<<build_grid, 256, 0, stream>>>(src, dst, E, Epb, partial, row_off,
                                              csr_src, npg, N);

    // pack x -> bf16 (gather payload halved)
    const int n4 = N * 32;
    pack_bf16<<<(n4 + 255) / 256, 256, 0, stream>>>(x, xb, n4);

    int aggGrid = (N + 3) / 4;
    int gemmGrid = (N + BM - 1) / BM;

    // layer 1
    agg_bf16<<<aggGrid, 256, 0, stream>>>((const uint*)xb, row_off, csr_src, aggn, N);
    gemm_dual<<<gemmGrid, 256, 0, stream>>>(aggn, x, Wl1, Wr1, b1, h1, h1b, N, 1);
    // layer 2
    agg_bf16<<<aggGrid, 256, 0, stream>>>((const uint*)h1b, row_off, csr_src, aggn, N);
    gemm_dual<<<gemmGrid, 256, 0, stream>>>(aggn, h1, Wl2, Wr2, b2, h2, nullptr, N, 1);
    // layer 3
    lin3_kernel<<<(N + 15) / 16, 256, 0, stream>>>(h2, Wl3, Wr3, b3, zr, N);
    out_kernel<<<(N * 8 + 255) / 256, 256, 0, stream>>>(zr, row_off, csr_src, (float*)d_out, N);
}

// Round 8
// 720.752 us; speedup vs baseline: 1.3236x; 1.1497x over previous
//
#include <hip/hip_runtime.h>
#include <hip/hip_bf16.h>

#define N_NODES 100000
#define G_PART 16     // node groups; npg = 6250 -> 25 KB LDS hist
#define B_PART 48     // blocks per group for count/fill; grid 768 = 3/CU
#define NPG_PAD 6272  // LDS capacity (>= ceil(N/G_PART))
#define A_BLOCKS 1024 // partition blocks

// ---------------------------------------------------------------- CSR build
// R5: device atomics are memory-side (~100MB of 32B HBM ops) -> LDS hist.
// R6: 50KB LDS -> 22% occupancy, latency-bound. R7: G=16 fixed occupancy but
// conditional non-nt src loads polluted L2 -> csr RMW write-amp returned
// (WRITE 97MB), and the G-fold edge re-sweep (~600MB redundant stream) is
// structural. R8: radix partition -- read edges once, bucket packed
// (d_local<<17)|src per group via per-(block,group) reserved segments
// (16 global atomics/block), then count/fill sweep only their bucket.

__global__ __launch_bounds__(256) void partition_edges(
    const int* __restrict__ src, const int* __restrict__ dst, int E,
    int* __restrict__ bkt, unsigned int* __restrict__ gcur, int cap, int npg) {
    __shared__ int cnt16[G_PART];
    __shared__ unsigned int base16[G_PART];
    __shared__ unsigned int cur16[G_PART];
    int tid = threadIdx.x;
    if (tid < G_PART) cnt16[tid] = 0;
    __syncthreads();
    int per = (E + A_BLOCKS - 1) / A_BLOCKS;
    int beg = blockIdx.x * per;
    int end = min(beg + per, E);
    // pass 1: count per group (block footprint 12.5 KB -> L1-resident)
    for (int i = beg + tid; i < end; i += 256) {
        int d = dst[i];
        atomicAdd(&cnt16[d / npg], 1);
    }
    __syncthreads();
    if (tid < G_PART) {
        base16[tid] = atomicAdd(&gcur[tid], (unsigned int)cnt16[tid]);
        cur16[tid] = 0;
    }
    __syncthreads();
    // pass 2: append packed (d_local<<17)|src to this block's reserved
    // segment in bucket g. Frontier-sequential writes -> L2 line merging.
    for (int i = beg + tid; i < end; i += 256) {
        int d = dst[i];
        int s = src[i];
        int g = d / npg;
        unsigned int p = base16[g] + atomicAdd(&cur16[g], 1u);
        bkt[(size_t)g * cap + p] = ((d - g * npg) << 17) | s;
    }
}

// count: block (g,b) sweeps its slice of bucket g (100% hits), LDS histogram,
// flush partial counts with plain coalesced stores.
__global__ __launch_bounds__(256) void count_hist(const int* __restrict__ bkt,
                                                  const unsigned int* __restrict__ gcur,
                                                  int cap, int* __restrict__ partial,
                                                  int npg, int N) {
    __shared__ int hist[NPG_PAD];
    int g = blockIdx.x & (G_PART - 1);
    int b = blockIdx.x / G_PART;
    int tid = threadIdx.x;
    for (int i = tid; i < npg; i += 256) hist[i] = 0;
    __syncthreads();
    int len = (int)gcur[g];
    int per = (len + B_PART - 1) / B_PART;
    int ibeg = b * per;
    int iend = min(ibeg + per, len);
    const int* bp = bkt + (size_t)g * cap;
    for (int i = ibeg + tid; i < iend; i += 256) {
        int v = __builtin_nontemporal_load(bp + i);
        atomicAdd(&hist[v >> 17], 1);
    }
    __syncthreads();
    int base = (g * B_PART + b) * npg;
    for (int j = tid; j < npg; j += 256) partial[base + j] = hist[j];
}

// per node: exclusive prefix across the B_PART block-partials (in place),
// total -> cnt. Coalesced: fixed b => adjacent nodes are adjacent addresses.
__global__ __launch_bounds__(256) void scan_partials(int* __restrict__ partial,
                                                     int* __restrict__ cnt,
                                                     int npg, int N) {
    int n = blockIdx.x * 256 + threadIdx.x;
    if (n >= N) return;
    int g = n / npg;
    int i = n - g * npg;
    size_t base = (size_t)g * B_PART * npg + i;
    int run = 0;
#pragma unroll 4
    for (int b = 0; b < B_PART; ++b) {
        size_t idx = base + (size_t)b * npg;
        int t = partial[idx];
        partial[idx] = run;
        run += t;
    }
    cnt[n] = run;
}

// fill: LDS cursor = row_off + per-block base; LDS atomicAdd for position;
// plain store to csr_src (positions disjoint across blocks by construction).
__global__ __launch_bounds__(256) void fill_hist(const int* __restrict__ bkt,
                                                 const unsigned int* __restrict__ gcur,
                                                 int cap, const int* __restrict__ partial,
                                                 const int* __restrict__ row_off,
                                                 int* __restrict__ csr_src,
                                                 int npg, int N) {
    __shared__ int cur[NPG_PAD];
    int g = blockIdx.x & (G_PART - 1);
    int b = blockIdx.x / G_PART;
    int lo = g * npg;
    int tid = threadIdx.x;
    int pbase = (g * B_PART + b) * npg;
    for (int i = tid; i < npg && lo + i < N; i += 256)
        cur[i] = row_off[lo + i] + partial[pbase + i];
    __syncthreads();
    int len = (int)gcur[g];
    int per = (len + B_PART - 1) / B_PART;
    int ibeg = b * per;
    int iend = min(ibeg + per, len);
    const int* bp = bkt + (size_t)g * cap;
    for (int i = ibeg + tid; i < iend; i += 256) {
        int v = __builtin_nontemporal_load(bp + i);
        int p = atomicAdd(&cur[v >> 17], 1);
        csr_src[p] = v & 0x1FFFF;
    }
}

// ---------------- grid-parallel exclusive scan (3 kernels, 1024 elems/block)
#define SCHUNK 1024

__global__ __launch_bounds__(256) void scan_blocks(const int* __restrict__ cnt,
                                                   int* __restrict__ row_off,
                                                   int* __restrict__ block_sums, int n) {
    __shared__ int ts[256];
    int tid = threadIdx.x;
    int base = blockIdx.x * SCHUNK + tid * 4;
    int v[4];
    int s = 0;
#pragma unroll
    for (int j = 0; j < 4; ++j) {
        int i = base + j;
        v[j] = (i < n) ? cnt[i] : 0;
        s += v[j];
    }
    ts[tid] = s;
    __syncthreads();
    for (int off = 1; off < 256; off <<= 1) {
        int t = 0;
        if (tid >= off) t = ts[tid - off];
        __syncthreads();
        if (tid >= off) ts[tid] += t;
        __syncthreads();
    }
    int run = (tid > 0) ? ts[tid - 1] : 0;
    if (tid == 255) block_sums[blockIdx.x] = ts[255];
#pragma unroll
    for (int j = 0; j < 4; ++j) {
        int i = base + j;
        if (i < n) row_off[i] = run;
        run += v[j];
    }
}

__global__ __launch_bounds__(256) void scan_sums(int* __restrict__ block_sums, int nb,
                                                 int* __restrict__ row_off, int n) {
    __shared__ int ts[256];
    int tid = threadIdx.x;
    int v = (tid < nb) ? block_sums[tid] : 0;
    ts[tid] = v;
    __syncthreads();
    for (int off = 1; off < 256; off <<= 1) {
        int t = 0;
        if (tid >= off) t = ts[tid - off];
        __syncthreads();
        if (tid >= off) ts[tid] += t;
        __syncthreads();
    }
    if (tid < nb) block_sums[tid] = (tid > 0) ? ts[tid - 1] : 0;
    if (tid == 255) row_off[n] = ts[255];
}

__global__ __launch_bounds__(256) void scan_add(int* __restrict__ row_off,
                                                const int* __restrict__ block_sums, int n) {
    int tid = threadIdx.x;
    int off = block_sums[blockIdx.x];
    int base = blockIdx.x * SCHUNK + tid * 4;
#pragma unroll
    for (int j = 0; j < 4; ++j) {
        int i = base + j;
        if (i < n) row_off[i] += off;
    }
}

// ---------------------------------------------------------------- bf16 pack
__global__ __launch_bounds__(256) void pack_bf16(const float* __restrict__ in,
                                                 uint2* __restrict__ out, int n4) {
    int i = blockIdx.x * 256 + threadIdx.x;
    if (i >= n4) return;
    float4 v = *(const float4*)&in[(size_t)i * 4];
    __hip_bfloat162 p0 = __float22bfloat162_rn(make_float2(v.x, v.y));
    __hip_bfloat162 p1 = __float22bfloat162_rn(make_float2(v.z, v.w));
    uint2 o;
    o.x = *(const uint*)&p0;
    o.y = *(const uint*)&p1;
    out[i] = o;
}

// ------------------------------------------------- mean aggregation, bf16 gather
static __device__ inline float2 unpack2(uint v) {
    float2 r;
    r.x = __uint_as_float(v << 16);
    r.y = __uint_as_float(v & 0xffff0000u);
    return r;
}

__global__ __launch_bounds__(256) void agg_bf16(const uint* __restrict__ featb,
                                                const int* __restrict__ row_off,
                                                const int* __restrict__ csr,
                                                float* __restrict__ outf, int M) {
    int node = blockIdx.x * 4 + (threadIdx.x >> 6);
    if (node >= M) return;
    int lane = threadIdx.x & 63;
    int beg = row_off[node], end = row_off[node + 1];
    float sx = 0.f, sy = 0.f;
    int i = beg;
    for (; i + 4 <= end; i += 4) {
        int s0 = csr[i], s1 = csr[i + 1], s2 = csr[i + 2], s3 = csr[i + 3];
        uint v0 = featb[(size_t)s0 * 64 + lane];
        uint v1 = featb[(size_t)s1 * 64 + lane];
        uint v2 = featb[(size_t)s2 * 64 + lane];
        uint v3 = featb[(size_t)s3 * 64 + lane];
        float2 f0 = unpack2(v0), f1 = unpack2(v1), f2 = unpack2(v2), f3 = unpack2(v3);
        sx += f0.x + f1.x + f2.x + f3.x;
        sy += f0.y + f1.y + f2.y + f3.y;
    }
    for (; i < end; ++i) {
        uint v = featb[(size_t)csr[i] * 64 + lane];
        float2 f = unpack2(v);
        sx += f.x;
        sy += f.y;
    }
    float inv = (end > beg) ? 1.0f / (float)(end - beg) : 0.0f;
    float2 o;
    o.x = sx * inv;
    o.y = sy * inv;
    ((float2*)outf)[(size_t)node * 64 + lane] = o;
}

// --------------------------------------------- fused dual GEMM: out = act(A1@W1^T + A2@W2^T + b)
#define BM 64
#define KB 32
__global__ __launch_bounds__(256) void gemm_dual(const float* __restrict__ A1,
                                                 const float* __restrict__ A2,
                                                 const float* __restrict__ W1,
                                                 const float* __restrict__ W2,
                                                 const float* __restrict__ bias,
                                                 float* __restrict__ out,
                                                 uint2* __restrict__ outb,   // nullable
                                                 int M, int relu) {
    __shared__ float As[KB][BM + 4];
    __shared__ float Ws[KB][128 + 4];
    int tid = threadIdx.x;
    int row0 = blockIdx.x * BM;
    int tr = tid >> 5;
    int tc = tid & 31;
    int r0 = tr * 8;
    int c0 = tc * 4;
    float acc[8][4];
#pragma unroll
    for (int i = 0; i < 8; ++i)
#pragma unroll
        for (int c = 0; c < 4; ++c) acc[i][c] = 0.f;

    for (int half = 0; half < 2; ++half) {
        const float* A = half ? A2 : A1;
        const float* W = half ? W2 : W1;
        for (int kc = 0; kc < 128; kc += KB) {
#pragma unroll
            for (int t = 0; t < 2; ++t) {
                int f = tid + t * 256;
                int r = f >> 3;
                int c4 = (f & 7) * 4;
                int gr = row0 + r;
                float4 v = make_float4(0.f, 0.f, 0.f, 0.f);
                if (gr < M) v = *(const float4*)&A[(size_t)gr * 128 + kc + c4];
                As[c4 + 0][r] = v.x;
                As[c4 + 1][r] = v.y;
                As[c4 + 2][r] = v.z;
                As[c4 + 3][r] = v.w;
            }
#pragma unroll
            for (int t = 0; t < 4; ++t) {
                int f = tid + t * 256;
                int j = f >> 3;
                int c4 = (f & 7) * 4;
                float4 v = *(const float4*)&W[(size_t)j * 128 + kc + c4];
                Ws[c4 + 0][j] = v.x;
                Ws[c4 + 1][j] = v.y;
                Ws[c4 + 2][j] = v.z;
                Ws[c4 + 3][j] = v.w;
            }
            __syncthreads();
#pragma unroll
            for (int k = 0; k < KB; ++k) {
                float4 a0 = *(const float4*)&As[k][r0];
                float4 a1 = *(const float4*)&As[k][r0 + 4];
                float4 bv = *(const float4*)&Ws[k][c0];
                float av[8] = {a0.x, a0.y, a0.z, a0.w, a1.x, a1.y, a1.z, a1.w};
                float bb[4] = {bv.x, bv.y, bv.z, bv.w};
#pragma unroll
                for (int i = 0; i < 8; ++i)
#pragma unroll
                    for (int c = 0; c < 4; ++c) acc[i][c] += av[i] * bb[c];
            }
            __syncthreads();
        }
    }
#pragma unroll
    for (int i = 0; i < 8; ++i) {
        int gr = row0 + r0 + i;
        if (gr < M) {
            float4 o;
            o.x = acc[i][0] + bias[c0 + 0];
            o.y = acc[i][1] + bias[c0 + 1];
            o.z = acc[i][2] + bias[c0 + 2];
            o.w = acc[i][3] + bias[c0 + 3];
            if (relu) {
                o.x = fmaxf(o.x, 0.f);
                o.y = fmaxf(o.y, 0.f);
                o.z = fmaxf(o.z, 0.f);
                o.w = fmaxf(o.w, 0.f);
            }
            *(float4*)&out[(size_t)gr * 128 + c0] = o;
            if (outb) {
                __hip_bfloat162 p0 = __float22bfloat162_rn(make_float2(o.x, o.y));
                __hip_bfloat162 p1 = __float22bfloat162_rn(make_float2(o.z, o.w));
                uint2 ob;
                ob.x = *(const uint*)&p0;
                ob.y = *(const uint*)&p1;
                outb[(size_t)gr * 32 + (c0 >> 2)] = ob;
            }
        }
    }
}

// ------------------------------------- layer 3 transform: zr[n][0..5]=h@Wl3^T, [6..11]=h@Wr3^T+b3
__global__ __launch_bounds__(256) void lin3_kernel(const float* __restrict__ h,
                                                   const float* __restrict__ Wl,
                                                   const float* __restrict__ Wr,
                                                   const float* __restrict__ b3,
                                                   float* __restrict__ zr, int M) {
    __shared__ float Ws[12][129];
    __shared__ float hs[16][132];
    int tid = threadIdx.x;
    for (int f = tid; f < 12 * 128; f += 256) {
        int j = f >> 7, k = f & 127;
        Ws[j][k] = (j < 6) ? Wl[j * 128 + k] : Wr[(j - 6) * 128 + k];
    }
    int node0 = blockIdx.x * 16;
#pragma unroll
    for (int t = 0; t < 2; ++t) {
        int f = tid + t * 256;
        int r = f >> 5;
        int c4 = (f & 31) * 4;
        int gn = node0 + r;
        float4 v = make_float4(0.f, 0.f, 0.f, 0.f);
        if (gn < M) v = *(const float4*)&h[(size_t)gn * 128 + c4];
        *(float4*)&hs[r][c4] = v;
    }
    __syncthreads();
    int ln = tid >> 4;
    int j = tid & 15;
    int gn = node0 + ln;
    if (j < 12 && gn < M) {
        float acc = 0.f;
#pragma unroll
        for (int k = 0; k < 128; ++k) acc += hs[ln][k] * Ws[j][k];
        if (j >= 6) acc += b3[j - 6];
        zr[(size_t)gn * 12 + j] = acc;
    }
}

// ------------------------------------------- final: out[n][j] = mean_s z[s][j] + r[n][j]
__global__ void out_kernel(const float* __restrict__ zr, const int* __restrict__ row_off,
                           const int* __restrict__ csr, float* __restrict__ out, int M) {
    int idx = blockIdx.x * blockDim.x + threadIdx.x;
    int node = idx >> 3;
    int j = idx & 7;
    if (node >= M || j >= 6) return;
    int beg = row_off[node], end = row_off[node + 1];
    float acc = 0.f;
    for (int i = beg; i < end; ++i) {
        int s = csr[i];
        acc += zr[(size_t)s * 12 + j];
    }
    float inv = (end > beg) ? 1.0f / (float)(end - beg) : 0.0f;
    out[(size_t)node * 6 + j] = acc * inv + zr[(size_t)node * 12 + 6 + j];
}

// ---------------------------------------------------------------- launch
static inline size_t align_up(size_t x, size_t a) { return (x + a - 1) & ~(a - 1); }

extern "C" void kernel_launch(void* const* d_in, const int* in_sizes, int n_in,
                              void* d_out, int out_size, void* d_ws, size_t ws_size,
                              hipStream_t stream) {
    const float* x = (const float*)d_in[0];
    const int* ei = (const int*)d_in[1];
    const float* Wl1 = (const float*)d_in[2];
    const float* Wr1 = (const float*)d_in[3];
    const float* b1 = (const float*)d_in[4];
    const float* Wl2 = (const float*)d_in[5];
    const float* Wr2 = (const float*)d_in[6];
    const float* b2 = (const float*)d_in[7];
    const float* Wl3 = (const float*)d_in[8];
    const float* Wr3 = (const float*)d_in[9];
    const float* b3 = (const float*)d_in[10];

    const int N = in_sizes[0] / 128;   // 100000
    const int E = in_sizes[1] / 2;     // 3200000
    const int* src = ei;
    const int* dst = ei + E;

    // workspace layout
    char* ws = (char*)d_ws;
    size_t off = 0;
    int* cnt = (int*)(ws + off);        off = align_up(off + (size_t)N * 4, 512);
    int* row_off = (int*)(ws + off);    off = align_up(off + (size_t)(N + 1) * 4, 512);
    int* block_sums = (int*)(ws + off); off = align_up(off + 512 * 4, 512);
    unsigned int* gcur = (unsigned int*)(ws + off); off = align_up(off + 64 * 4, 512);
    int* csr_src = (int*)(ws + off);    off = align_up(off + (size_t)E * 4, 512);
    float* aggn = (float*)(ws + off);   off = align_up(off + (size_t)N * 128 * 4, 512);
    float* h1 = (float*)(ws + off);     off = align_up(off + (size_t)N * 128 * 4, 512);
    float* h2 = (float*)(ws + off);     off = align_up(off + (size_t)N * 128 * 4, 512);
    float* zr = (float*)(ws + off);     off = align_up(off + (size_t)N * 12 * 4, 512);
    uint2* h1b = (uint2*)(ws + off);    off = align_up(off + (size_t)N * 128 * 2, 512);
    // partial aliases aggn: live [count,fill]; aggn live [agg1,gemm2] — disjoint.
    // size: G*B*npg = 16*48*6250*4 = 19.2 MB < 51.2 MB ✓
    int* partial = (int*)aggn;
    // bkt aliases h1: live [partition,fill]; h1 live [gemm1,gemm2] — disjoint.
    // size: 16*210000*4 = 13.44 MB < 51.2 MB ✓ (bucket mean 200k, +23 sigma)
    const int cap = 210000;
    int* bkt = (int*)h1;
    // xb aliases h2: live [pack,agg1]; h2 live [gemm2,out] — disjoint.
    uint2* xb = (uint2*)h2;
    (void)ws_size;

    // --- CSR build: radix partition + LDS histogram, no per-edge global atomics
    const int npg = (N + G_PART - 1) / G_PART;       // 6250 (<= NPG_PAD)
    const int build_grid = G_PART * B_PART;          // 768 blocks = 3/CU

    hipMemsetAsync(gcur, 0, G_PART * 4, stream);
    partition_edges<<<A_BLOCKS, 256, 0, stream>>>(src, dst, E, bkt, gcur, cap, npg);
    count_hist<<<build_grid, 256, 0, stream>>>(bkt, gcur, cap, partial, npg, N);
    scan_partials<<<(N + 255) / 256, 256, 0, stream>>>(partial, cnt, npg, N);

    const int nscan = (N + SCHUNK - 1) / SCHUNK;
    scan_blocks<<<nscan, 256, 0, stream>>>(cnt, row_off, block_sums, N);
    scan_sums<<<1, 256, 0, stream>>>(block_sums, nscan, row_off, N);
    scan_add<<<nscan, 256, 0, stream>>>(row_off, block_sums, N);

    fill_hist<<<build_grid, 256, 0, stream>>>(bkt, gcur, cap, partial, row_off,
                                              csr_src, npg, N);

    // pack x -> bf16 (gather payload halved)
    const int n4 = N * 32;
    pack_bf16<<<(n4 + 255) / 256, 256, 0, stream>>>(x, xb, n4);

    int aggGrid = (N + 3) / 4;
    int gemmGrid = (N + BM - 1) / BM;

    // layer 1
    agg_bf16<<<aggGrid, 256, 0, stream>>>((const uint*)xb, row_off, csr_src, aggn, N);
    gemm_dual<<<gemmGrid, 256, 0, stream>>>(aggn, x, Wl1, Wr1, b1, h1, h1b, N, 1);
    // layer 2
    agg_bf16<<<aggGrid, 256, 0, stream>>>((const uint*)h1b, row_off, csr_src, aggn, N);
    gemm_dual<<<gemmGrid, 256, 0, stream>>>(aggn, h1, Wl2, Wr2, b2, h2, nullptr, N, 1);
    // layer 3
    lin3_kernel<<<(N + 15) / 16, 256, 0, stream>>>(h2, Wl3, Wr3, b3, zr, N);
    out_kernel<<<(N * 8 + 255) / 256, 256, 0, stream>>>(zr, row_off, csr_src, (float*)d_out, N);
}

// Round 9
// 660.368 us; speedup vs baseline: 1.4446x; 1.0914x over previous
//
#include <hip/hip_runtime.h>
#include <hip/hip_bf16.h>

#define N_NODES 100000
#define G_PART 16     // node groups; npg = 6250 -> 25 KB LDS hist
#define B_PART 48     // blocks per group for count/fill; grid 768 = 3/CU
#define NPG_PAD 6272  // LDS capacity (>= ceil(N/G_PART))
#define A_BLOCKS 1024 // partition blocks

// ---------------------------------------------------------------- CSR build
// R5: device atomics are memory-side -> LDS hist. R6: occupancy. R7: don't
// pollute L2 with the stream. R8: radix partition, edges read ~once.
__global__ __launch_bounds__(256) void partition_edges(
    const int* __restrict__ src, const int* __restrict__ dst, int E,
    int* __restrict__ bkt, unsigned int* __restrict__ gcur, int cap, int npg) {
    __shared__ int cnt16[G_PART];
    __shared__ unsigned int base16[G_PART];
    __shared__ unsigned int cur16[G_PART];
    int tid = threadIdx.x;
    if (tid < G_PART) cnt16[tid] = 0;
    __syncthreads();
    int per = (E + A_BLOCKS - 1) / A_BLOCKS;
    int beg = blockIdx.x * per;
    int end = min(beg + per, E);
    for (int i = beg + tid; i < end; i += 256) {
        int d = dst[i];
        atomicAdd(&cnt16[d / npg], 1);
    }
    __syncthreads();
    if (tid < G_PART) {
        base16[tid] = atomicAdd(&gcur[tid], (unsigned int)cnt16[tid]);
        cur16[tid] = 0;
    }
    __syncthreads();
    for (int i = beg + tid; i < end; i += 256) {
        int d = dst[i];
        int s = src[i];
        int g = d / npg;
        unsigned int p = base16[g] + atomicAdd(&cur16[g], 1u);
        bkt[(size_t)g * cap + p] = ((d - g * npg) << 17) | s;
    }
}

__global__ __launch_bounds__(256) void count_hist(const int* __restrict__ bkt,
                                                  const unsigned int* __restrict__ gcur,
                                                  int cap, int* __restrict__ partial,
                                                  int npg, int N) {
    __shared__ int hist[NPG_PAD];
    int g = blockIdx.x & (G_PART - 1);
    int b = blockIdx.x / G_PART;
    int tid = threadIdx.x;
    for (int i = tid; i < npg; i += 256) hist[i] = 0;
    __syncthreads();
    int len = (int)gcur[g];
    int per = (len + B_PART - 1) / B_PART;
    int ibeg = b * per;
    int iend = min(ibeg + per, len);
    const int* bp = bkt + (size_t)g * cap;
    for (int i = ibeg + tid; i < iend; i += 256) {
        int v = __builtin_nontemporal_load(bp + i);
        atomicAdd(&hist[v >> 17], 1);
    }
    __syncthreads();
    int base = (g * B_PART + b) * npg;
    for (int j = tid; j < npg; j += 256) partial[base + j] = hist[j];
}

__global__ __launch_bounds__(256) void scan_partials(int* __restrict__ partial,
                                                     int* __restrict__ cnt,
                                                     int npg, int N) {
    int n = blockIdx.x * 256 + threadIdx.x;
    if (n >= N) return;
    int g = n / npg;
    int i = n - g * npg;
    size_t base = (size_t)g * B_PART * npg + i;
    int run = 0;
#pragma unroll 4
    for (int b = 0; b < B_PART; ++b) {
        size_t idx = base + (size_t)b * npg;
        int t = partial[idx];
        partial[idx] = run;
        run += t;
    }
    cnt[n] = run;
}

__global__ __launch_bounds__(256) void fill_hist(const int* __restrict__ bkt,
                                                 const unsigned int* __restrict__ gcur,
                                                 int cap, const int* __restrict__ partial,
                                                 const int* __restrict__ row_off,
                                                 int* __restrict__ csr_src,
                                                 int npg, int N) {
    __shared__ int cur[NPG_PAD];
    int g = blockIdx.x & (G_PART - 1);
    int b = blockIdx.x / G_PART;
    int lo = g * npg;
    int tid = threadIdx.x;
    int pbase = (g * B_PART + b) * npg;
    for (int i = tid; i < npg && lo + i < N; i += 256)
        cur[i] = row_off[lo + i] + partial[pbase + i];
    __syncthreads();
    int len = (int)gcur[g];
    int per = (len + B_PART - 1) / B_PART;
    int ibeg = b * per;
    int iend = min(ibeg + per, len);
    const int* bp = bkt + (size_t)g * cap;
    for (int i = ibeg + tid; i < iend; i += 256) {
        int v = __builtin_nontemporal_load(bp + i);
        int p = atomicAdd(&cur[v >> 17], 1);
        csr_src[p] = v & 0x1FFFF;
    }
}

// ---------------- grid-parallel exclusive scan (3 kernels, 1024 elems/block)
#define SCHUNK 1024

__global__ __launch_bounds__(256) void scan_blocks(const int* __restrict__ cnt,
                                                   int* __restrict__ row_off,
                                                   int* __restrict__ block_sums, int n) {
    __shared__ int ts[256];
    int tid = threadIdx.x;
    int base = blockIdx.x * SCHUNK + tid * 4;
    int v[4];
    int s = 0;
#pragma unroll
    for (int j = 0; j < 4; ++j) {
        int i = base + j;
        v[j] = (i < n) ? cnt[i] : 0;
        s += v[j];
    }
    ts[tid] = s;
    __syncthreads();
    for (int off = 1; off < 256; off <<= 1) {
        int t = 0;
        if (tid >= off) t = ts[tid - off];
        __syncthreads();
        if (tid >= off) ts[tid] += t;
        __syncthreads();
    }
    int run = (tid > 0) ? ts[tid - 1] : 0;
    if (tid == 255) block_sums[blockIdx.x] = ts[255];
#pragma unroll
    for (int j = 0; j < 4; ++j) {
        int i = base + j;
        if (i < n) row_off[i] = run;
        run += v[j];
    }
}

__global__ __launch_bounds__(256) void scan_sums(int* __restrict__ block_sums, int nb,
                                                 int* __restrict__ row_off, int n) {
    __shared__ int ts[256];
    int tid = threadIdx.x;
    int v = (tid < nb) ? block_sums[tid] : 0;
    ts[tid] = v;
    __syncthreads();
    for (int off = 1; off < 256; off <<= 1) {
        int t = 0;
        if (tid >= off) t = ts[tid - off];
        __syncthreads();
        if (tid >= off) ts[tid] += t;
        __syncthreads();
    }
    if (tid < nb) block_sums[tid] = (tid > 0) ? ts[tid - 1] : 0;
    if (tid == 255) row_off[n] = ts[255];
}

__global__ __launch_bounds__(256) void scan_add(int* __restrict__ row_off,
                                                const int* __restrict__ block_sums, int n) {
    int tid = threadIdx.x;
    int off = block_sums[blockIdx.x];
    int base = blockIdx.x * SCHUNK + tid * 4;
#pragma unroll
    for (int j = 0; j < 4; ++j) {
        int i = base + j;
        if (i < n) row_off[i] += off;
    }
}

// ---------------------------------------------------------------- bf16 pack
__global__ __launch_bounds__(256) void pack_bf16(const float* __restrict__ in,
                                                 uint2* __restrict__ out, int n4) {
    int i = blockIdx.x * 256 + threadIdx.x;
    if (i >= n4) return;
    float4 v = *(const float4*)&in[(size_t)i * 4];
    __hip_bfloat162 p0 = __float22bfloat162_rn(make_float2(v.x, v.y));
    __hip_bfloat162 p1 = __float22bfloat162_rn(make_float2(v.z, v.w));
    uint2 o;
    o.x = *(const uint*)&p0;
    o.y = *(const uint*)&p1;
    out[i] = o;
}

// pack weights: Wc[n][k] bf16, k<128 -> Wl[n][k], else Wr[n][k-128]
__global__ __launch_bounds__(256) void pack_w(const float* __restrict__ Wl,
                                              const float* __restrict__ Wr,
                                              unsigned short* __restrict__ Wc) {
    int idx = blockIdx.x * 256 + threadIdx.x;
    if (idx >= 128 * 256) return;
    int n = idx >> 8, k = idx & 255;
    float v = (k < 128) ? Wl[n * 128 + k] : Wr[n * 128 + (k - 128)];
    __hip_bfloat16 b = __float2bfloat16(v);
    Wc[idx] = *(const unsigned short*)&b;
}

// ------------------------------------------------- mean aggregation, bf16 in/out
static __device__ inline float2 unpack2(uint v) {
    float2 r;
    r.x = __uint_as_float(v << 16);
    r.y = __uint_as_float(v & 0xffff0000u);
    return r;
}

__global__ __launch_bounds__(256) void agg_bf16(const uint* __restrict__ featb,
                                                const int* __restrict__ row_off,
                                                const int* __restrict__ csr,
                                                uint* __restrict__ outb, int M) {
    int node = blockIdx.x * 4 + (threadIdx.x >> 6);
    if (node >= M) return;
    int lane = threadIdx.x & 63;
    int beg = row_off[node], end = row_off[node + 1];
    float sx = 0.f, sy = 0.f;
    int i = beg;
    for (; i + 4 <= end; i += 4) {
        int s0 = csr[i], s1 = csr[i + 1], s2 = csr[i + 2], s3 = csr[i + 3];
        uint v0 = featb[(size_t)s0 * 64 + lane];
        uint v1 = featb[(size_t)s1 * 64 + lane];
        uint v2 = featb[(size_t)s2 * 64 + lane];
        uint v3 = featb[(size_t)s3 * 64 + lane];
        float2 f0 = unpack2(v0), f1 = unpack2(v1), f2 = unpack2(v2), f3 = unpack2(v3);
        sx += f0.x + f1.x + f2.x + f3.x;
        sy += f0.y + f1.y + f2.y + f3.y;
    }
    for (; i < end; ++i) {
        uint v = featb[(size_t)csr[i] * 64 + lane];
        float2 f = unpack2(v);
        sx += f.x;
        sy += f.y;
    }
    float inv = (end > beg) ? 1.0f / (float)(end - beg) : 0.0f;
    __hip_bfloat162 p = __float22bfloat162_rn(make_float2(sx * inv, sy * inv));
    outb[(size_t)node * 64 + lane] = *(const uint*)&p;
}

// --------------------------------------------- MFMA bf16 GEMM (LDS-free)
// out[m][n] = act(sum_k [Aagg|Aself][m][k] * Wc[n][k] + bias[n])
// A-frag: lane holds A[m=lane&15][k=quad*8+j] (16B load, k-contiguous).
// B-frag: lane holds Wc[n=lane&15][k=quad*8+j] (W is [128][256] row-major).
// C/D: col=lane&15, row=quad*4+reg (learn_hip m89/m120 verified layouts).
typedef __attribute__((ext_vector_type(8))) short bfrag8;
typedef __attribute__((ext_vector_type(4))) float f32x4;

__global__ __launch_bounds__(256) void gemm_mfma(
    const unsigned short* __restrict__ Aagg,   // [M][128] bf16
    const unsigned short* __restrict__ Aself,  // [M][128] bf16
    const unsigned short* __restrict__ Wc,     // [128][256] bf16
    const float* __restrict__ bias,            // [128]
    float* __restrict__ outf,                  // nullable [M][128] fp32
    unsigned short* __restrict__ outb,         // nullable [M][128] bf16
    int M, int relu) {
    int wave = threadIdx.x >> 6;
    int lane = threadIdx.x & 63;
    int m0 = blockIdx.x * 64 + wave * 16;
    int mrow = lane & 15;
    int quad = lane >> 4;
    int row = m0 + mrow;
    int rclamp = (row < M) ? row : 0;

    f32x4 acc[8];
#pragma unroll
    for (int t = 0; t < 8; ++t) acc[t] = (f32x4){0.f, 0.f, 0.f, 0.f};

    const unsigned short* arow0 = Aagg + (size_t)rclamp * 128;
    const unsigned short* arow1 = Aself + (size_t)rclamp * 128;
#pragma unroll
    for (int ks = 0; ks < 8; ++ks) {
        int k0 = ks * 32;
        const unsigned short* ap =
            (k0 < 128) ? (arow0 + k0 + quad * 8) : (arow1 + (k0 - 128) + quad * 8);
        bfrag8 af = *(const bfrag8*)ap;
#pragma unroll
        for (int t = 0; t < 8; ++t) {
            const unsigned short* bp = Wc + (size_t)(t * 16 + mrow) * 256 + k0 + quad * 8;
            bfrag8 bf = *(const bfrag8*)bp;
            acc[t] = __builtin_amdgcn_mfma_f32_16x16x32_bf16(af, bf, acc[t], 0, 0, 0);
        }
    }
#pragma unroll
    for (int t = 0; t < 8; ++t) {
        int col = t * 16 + mrow;
        float bcol = bias[col];
#pragma unroll
        for (int r = 0; r < 4; ++r) {
            int orow = m0 + quad * 4 + r;
            if (orow < M) {
                float v = acc[t][r] + bcol;
                if (relu) v = fmaxf(v, 0.f);
                if (outf) outf[(size_t)orow * 128 + col] = v;
                if (outb) {
                    __hip_bfloat16 hb = __float2bfloat16(v);
                    outb[(size_t)orow * 128 + col] = *(const unsigned short*)&hb;
                }
            }
        }
    }
}

// ------------------------------------- layer 3 transform: zr[n][0..5]=h@Wl3^T, [6..11]=h@Wr3^T+b3
__global__ __launch_bounds__(256) void lin3_kernel(const float* __restrict__ h,
                                                   const float* __restrict__ Wl,
                                                   const float* __restrict__ Wr,
                                                   const float* __restrict__ b3,
                                                   float* __restrict__ zr, int M) {
    __shared__ float Ws[12][129];
    __shared__ float hs[16][132];
    int tid = threadIdx.x;
    for (int f = tid; f < 12 * 128; f += 256) {
        int j = f >> 7, k = f & 127;
        Ws[j][k] = (j < 6) ? Wl[j * 128 + k] : Wr[(j - 6) * 128 + k];
    }
    int node0 = blockIdx.x * 16;
#pragma unroll
    for (int t = 0; t < 2; ++t) {
        int f = tid + t * 256;
        int r = f >> 5;
        int c4 = (f & 31) * 4;
        int gn = node0 + r;
        float4 v = make_float4(0.f, 0.f, 0.f, 0.f);
        if (gn < M) v = *(const float4*)&h[(size_t)gn * 128 + c4];
        *(float4*)&hs[r][c4] = v;
    }
    __syncthreads();
    int ln = tid >> 4;
    int j = tid & 15;
    int gn = node0 + ln;
    if (j < 12 && gn < M) {
        float acc = 0.f;
#pragma unroll
        for (int k = 0; k < 128; ++k) acc += hs[ln][k] * Ws[j][k];
        if (j >= 6) acc += b3[j - 6];
        zr[(size_t)gn * 12 + j] = acc;
    }
}

// ------------------------------------------- final: out[n][j] = mean_s z[s][j] + r[n][j]
__global__ void out_kernel(const float* __restrict__ zr, const int* __restrict__ row_off,
                           const int* __restrict__ csr, float* __restrict__ out, int M) {
    int idx = blockIdx.x * blockDim.x + threadIdx.x;
    int node = idx >> 3;
    int j = idx & 7;
    if (node >= M || j >= 6) return;
    int beg = row_off[node], end = row_off[node + 1];
    float acc = 0.f;
    for (int i = beg; i < end; ++i) {
        int s = csr[i];
        acc += zr[(size_t)s * 12 + j];
    }
    float inv = (end > beg) ? 1.0f / (float)(end - beg) : 0.0f;
    out[(size_t)node * 6 + j] = acc * inv + zr[(size_t)node * 12 + 6 + j];
}

// ---------------------------------------------------------------- launch
static inline size_t align_up(size_t x, size_t a) { return (x + a - 1) & ~(a - 1); }

extern "C" void kernel_launch(void* const* d_in, const int* in_sizes, int n_in,
                              void* d_out, int out_size, void* d_ws, size_t ws_size,
                              hipStream_t stream) {
    const float* x = (const float*)d_in[0];
    const int* ei = (const int*)d_in[1];
    const float* Wl1 = (const float*)d_in[2];
    const float* Wr1 = (const float*)d_in[3];
    const float* b1 = (const float*)d_in[4];
    const float* Wl2 = (const float*)d_in[5];
    const float* Wr2 = (const float*)d_in[6];
    const float* b2 = (const float*)d_in[7];
    const float* Wl3 = (const float*)d_in[8];
    const float* Wr3 = (const float*)d_in[9];
    const float* b3 = (const float*)d_in[10];

    const int N = in_sizes[0] / 128;   // 100000
    const int E = in_sizes[1] / 2;     // 3200000
    const int* src = ei;
    const int* dst = ei + E;

    // workspace layout
    char* ws = (char*)d_ws;
    size_t off = 0;
    int* cnt = (int*)(ws + off);        off = align_up(off + (size_t)N * 4, 512);
    int* row_off = (int*)(ws + off);    off = align_up(off + (size_t)(N + 1) * 4, 512);
    int* block_sums = (int*)(ws + off); off = align_up(off + 512 * 4, 512);
    unsigned int* gcur = (unsigned int*)(ws + off); off = align_up(off + 64 * 4, 512);
    unsigned short* Wc1 = (unsigned short*)(ws + off); off = align_up(off + 128 * 256 * 2, 512);
    unsigned short* Wc2 = (unsigned short*)(ws + off); off = align_up(off + 128 * 256 * 2, 512);
    int* csr_src = (int*)(ws + off);    off = align_up(off + (size_t)E * 4, 512);
    float* slotA = (float*)(ws + off);  off = align_up(off + (size_t)N * 128 * 4, 512);
    float* slotB = (float*)(ws + off);  off = align_up(off + (size_t)N * 128 * 4, 512);
    float* h2 = (float*)(ws + off);     off = align_up(off + (size_t)N * 128 * 4, 512);
    float* zr = (float*)(ws + off);     off = align_up(off + (size_t)N * 12 * 4, 512);
    uint2* h1b = (uint2*)(ws + off);    off = align_up(off + (size_t)N * 128 * 2, 512);
    // aliases (all lifetimes disjoint):
    //  partial on slotA [count..fill];  aggb on slotA [agg1..gemm1, agg2..gemm2]
    //  bkt on slotB [partition..fill]
    //  xb on h2 [pack..gemm1]; h2 written at gemm2
    int* partial = (int*)slotA;               // 16*48*6250*4 = 19.2 MB
    uint* aggb = (uint*)slotA;                // 25.6 MB
    const int cap = 210000;
    int* bkt = (int*)slotB;                   // 13.44 MB
    uint2* xb = (uint2*)h2;
    (void)ws_size;

    // --- CSR build: radix partition + LDS histogram, no per-edge global atomics
    const int npg = (N + G_PART - 1) / G_PART;       // 6250
    const int build_grid = G_PART * B_PART;          // 768

    hipMemsetAsync(gcur, 0, G_PART * 4, stream);
    partition_edges<<<A_BLOCKS, 256, 0, stream>>>(src, dst, E, bkt, gcur, cap, npg);
    count_hist<<<build_grid, 256, 0, stream>>>(bkt, gcur, cap, partial, npg, N);
    scan_partials<<<(N + 255) / 256, 256, 0, stream>>>(partial, cnt, npg, N);

    const int nscan = (N + SCHUNK - 1) / SCHUNK;
    scan_blocks<<<nscan, 256, 0, stream>>>(cnt, row_off, block_sums, N);
    scan_sums<<<1, 256, 0, stream>>>(block_sums, nscan, row_off, N);
    scan_add<<<nscan, 256, 0, stream>>>(row_off, block_sums, N);

    fill_hist<<<build_grid, 256, 0, stream>>>(bkt, gcur, cap, partial, row_off,
                                              csr_src, npg, N);

    // packs
    const int n4 = N * 32;
    pack_bf16<<<(n4 + 255) / 256, 256, 0, stream>>>(x, xb, n4);
    pack_w<<<128, 256, 0, stream>>>(Wl1, Wr1, Wc1);
    pack_w<<<128, 256, 0, stream>>>(Wl2, Wr2, Wc2);

    int aggGrid = (N + 3) / 4;
    int gemmGrid = (N + 63) / 64;

    // layer 1: agg(bf16)->aggb; MFMA gemm -> h1b (bf16 only)
    agg_bf16<<<aggGrid, 256, 0, stream>>>((const uint*)xb, row_off, csr_src, aggb, N);
    gemm_mfma<<<gemmGrid, 256, 0, stream>>>((const unsigned short*)aggb,
                                            (const unsigned short*)xb, Wc1, b1,
                                            nullptr, (unsigned short*)h1b, N, 1);
    // layer 2: agg(bf16 h1b)->aggb; MFMA gemm -> h2 (fp32 for lin3)
    agg_bf16<<<aggGrid, 256, 0, stream>>>((const uint*)h1b, row_off, csr_src, aggb, N);
    gemm_mfma<<<gemmGrid, 256, 0, stream>>>((const unsigned short*)aggb,
                                            (const unsigned short*)h1b, Wc2, b2,
                                            h2, nullptr, N, 1);
    // layer 3
    lin3_kernel<<<(N + 15) / 16, 256, 0, stream>>>(h2, Wl3, Wr3, b3, zr, N);
    out_kernel<<<(N * 8 + 255) / 256, 256, 0, stream>>>(zr, row_off, csr_src, (float*)d_out, N);
}